// Round 9
// baseline (57.739 us; speedup 1.0000x reference)
//
#include <hip/hip_runtime.h>
#include <math.h>

#define NP 100
#define NPILLAR 24000
#define OUT_CH 64
#define NTOTAL 2400000.0            // bs*V*P
#define VXc 0.2f
#define VYc 0.2f
#define XOFF 0.1f
#define YOFF (-39.9f)
#define BN_EPS 1e-3
#define G1 768
#define NW1 (G1 * 4)
#define G2 1024
#define NW2 (G2 * 4)

typedef __attribute__((ext_vector_type(8))) short bf16x8;
typedef __attribute__((ext_vector_type(16))) float f32x16;
typedef __attribute__((ext_vector_type(4))) unsigned int uint4v;

__device__ __forceinline__ unsigned int f2bf(float x) {
    unsigned int b = __builtin_bit_cast(unsigned int, x);
    b += 0x7FFFu + ((b >> 16) & 1u);   // RNE
    return b >> 16;
}
__device__ __forceinline__ unsigned int pk2(float a, float b) {
    return f2bf(a) | (f2bf(b) << 16);
}

__device__ __forceinline__ void build_f(const float4 p, float mx, float my, float mz,
                                        float cx, float cy, float* f) {
    f[0] = p.x; f[1] = p.y; f[2] = p.z; f[3] = p.w;
    f[4] = p.x - mx; f[5] = p.y - my; f[6] = p.z - mz;
    f[7] = p.x - cx; f[8] = p.y - cy;
}

__device__ __forceinline__ void moments(float* s, const float* f) {
    int k = 9;
#pragma unroll
    for (int i = 0; i < 9; ++i) {
        s[i] += f[i];
#pragma unroll
        for (int j = i; j < 9; ++j) { s[k] = fmaf(f[i], f[j], s[k]); ++k; }
    }
}

// ---- K1 (round-7 proven): 54 moments of the 9-dim augmented feature + meta --
// CRITICAL reference semantics: per-pillar mean sums ALL NP points (mask is
// applied after concat), divided by max(n,1). Moments predicated on valid.
__global__ __launch_bounds__(256, 4) void pfn_stats(
    const float4* __restrict__ feat, const int* __restrict__ npts,
    const int* __restrict__ coors, float4* __restrict__ meta,
    double* __restrict__ tot)
{
    const int tid = threadIdx.x;
    const int lane = tid & 63;
    const int wv = tid >> 6;
    const int gw = blockIdx.x * 4 + wv;

    float s[54];
#pragma unroll
    for (int i = 0; i < 54; ++i) s[i] = 0.f;

    for (int pv = gw; pv < NPILLAR; pv += NW1) {
        const float4* fp = feat + (size_t)pv * NP;
        float4 p0 = fp[lane];
        float4 p1 = (lane + 64 < NP) ? fp[lane + 64] : make_float4(0.f, 0.f, 0.f, 0.f);

        // mean over ALL NP points (reference), div by max(n,1)
        float sx = p0.x + p1.x, sy = p0.y + p1.y, sz = p0.z + p1.z;
#pragma unroll
        for (int off = 32; off; off >>= 1) {
            sx += __shfl_xor(sx, off);
            sy += __shfl_xor(sy, off);
            sz += __shfl_xor(sz, off);
        }
        int np_ = npts[pv];
        if (np_ > NP) np_ = NP;
        float inv = 1.f / fmaxf((float)np_, 1.f);
        float mx = sx * inv, my = sy * inv, mz = sz * inv;
        float cx = (float)coors[pv * 4 + 2] * VXc + XOFF;
        float cy = (float)coors[pv * 4 + 1] * VYc + YOFF;
        if (lane == 0) {
            meta[2 * pv]     = make_float4(mx, my, mz, __int_as_float(np_));
            meta[2 * pv + 1] = make_float4(cx, cy, 0.f, 0.f);
        }

        float f[9];
        if (lane < np_) {
            build_f(p0, mx, my, mz, cx, cy, f);
            moments(s, f);
        }
        if (lane + 64 < np_) {
            build_f(p1, mx, my, mz, cx, cy, f);
            moments(s, f);
        }
    }

#pragma unroll
    for (int i = 0; i < 54; ++i) {
#pragma unroll
        for (int off = 32; off; off >>= 1) s[i] += __shfl_xor(s[i], off);
    }
    __shared__ float red[4][54];
    if (lane == 0) {
#pragma unroll
        for (int i = 0; i < 54; ++i) red[wv][i] = s[i];
    }
    __syncthreads();
    if (tid < 54) {
        atomicAdd(&tot[tid],
                  (double)(red[0][tid] + red[1][tid] + red[2][tid] + red[3][tid]));
    }
}

// ---- K2: per-lane scsh from 54 moments, rank-5 MFMA (bias+flag column) -----
__global__ __launch_bounds__(256) void pfn_apply(
    const float4* __restrict__ feat, const float4* __restrict__ meta,
    const double* __restrict__ tot, const float* __restrict__ W,
    const float* __restrict__ gamma, const float* __restrict__ beta,
    float* __restrict__ out)
{
    const int tid = threadIdx.x;
    const int lane = tid & 63;
    const int wv = tid >> 6;
    const int gw = blockIdx.x * 4 + wv;
    const int col = lane & 31;
    const bool lo = (lane < 32);

    // --- per-lane channel c = lane: BN scale/shift (round-7 formula) ---
    float scl, shf;
    {
        double w[9];
#pragma unroll
        for (int i = 0; i < 9; ++i) w[i] = (double)W[i * OUT_CH + lane];
        double mean = 0.0;
#pragma unroll
        for (int i = 0; i < 9; ++i) mean += tot[i] * w[i];
        mean /= NTOTAL;
        double ex2 = 0.0;
        int k = 9;
#pragma unroll
        for (int i = 0; i < 9; ++i) {
#pragma unroll
            for (int j = i; j < 9; ++j) {
                ex2 += (i == j ? 1.0 : 2.0) * tot[k] * w[i] * w[j];
                ++k;
            }
        }
        ex2 /= NTOTAL;
        double var = ex2 - mean * mean;
        double scaled = (double)gamma[lane] / sqrt(var + BN_EPS);
        scl = (float)scaled;
        shf = (float)((double)beta[lane] - mean * scaled);
    }

    // effective rank-4 scaled weights + per-pillar-bias weights (own channel)
    float w0f = W[0 * OUT_CH + lane], w1f = W[1 * OUT_CH + lane];
    float w2f = W[2 * OUT_CH + lane], w3f = W[3 * OUT_CH + lane];
    float w4f = W[4 * OUT_CH + lane], w5f = W[5 * OUT_CH + lane];
    float w6f = W[6 * OUT_CH + lane], w7f = W[7 * OUT_CH + lane];
    float w8f = W[8 * OUT_CH + lane];
    float we0 = (w0f + w4f + w7f) * scl;
    float we1 = (w1f + w5f + w8f) * scl;
    float we2 = (w2f + w6f) * scl;
    float we3 = w3f * scl;
    float u4 = w4f * scl, u5 = w5f * scl, u6 = w6f * scl;
    float u7 = w7f * scl, u8 = w8f * scl;

    // B fragments (static part): channels col (B0) and col+32 (B1)
    float a0 = __shfl(we0, col),      a1 = __shfl(we1, col);
    float a2 = __shfl(we2, col),      a3 = __shfl(we3, col);
    float b0 = __shfl(we0, col + 32), b1 = __shfl(we1, col + 32);
    float b2 = __shfl(we2, col + 32), b3 = __shfl(we3, col + 32);
    const unsigned B0w0 = lo ? pk2(a0, a1) : 0u;
    const unsigned B0w1 = lo ? pk2(a2, a3) : 0u;
    const unsigned B1w0 = lo ? pk2(b0, b1) : 0u;
    const unsigned B1w1 = lo ? pk2(b2, b3) : 0u;

    f32x16 cz;
#pragma unroll
    for (int i = 0; i < 16; ++i) cz[i] = 0.f;

    for (int pv = gw; pv < NPILLAR; pv += NW2) {
        const float4* fp = feat + (size_t)pv * NP;
        float4 p0 = fp[lane];
        float4 p1 = (lane + 64 < NP) ? fp[lane + 64] : make_float4(0.f, 0.f, 0.f, 0.f);
        float4 m1 = meta[2 * pv];
        float4 m2 = meta[2 * pv + 1];
        const int np_ = __float_as_int(m1.w);

        // per-pillar scaled bias (own channel) -> k=4 slot of B
        float bsc = -(m1.x * u4 + m1.y * u5 + m1.z * u6 + m2.x * u7 + m2.y * u8);
        unsigned bbf = f2bf(bsc);
        unsigned bhi = (unsigned)__shfl((int)bbf, col + 32);
        uint4v bv0 = {B0w0, B0w1, lo ? bbf : 0u, 0u};
        uint4v bv1 = {B1w0, B1w1, lo ? bhi : 0u, 0u};
        bf16x8 bfr0 = __builtin_bit_cast(bf16x8, bv0);
        bf16x8 bfr1 = __builtin_bit_cast(bf16x8, bv1);

        // A rows: raw4 + valid flag at k=4; invalid rows all-zero -> x = 0
        bool v0 = lane < np_, v1 = (lane + 64) < np_;
        unsigned Ar0 = v0 ? pk2(p0.x, p0.y) : 0u;
        unsigned Ar1 = v0 ? pk2(p0.z, p0.w) : 0u;
        unsigned Ar2 = v0 ? 0x3F80u : 0u;           // bf16 1.0
        unsigned Br0 = v1 ? pk2(p1.x, p1.y) : 0u;
        unsigned Br1 = v1 ? pk2(p1.z, p1.w) : 0u;
        unsigned Br2 = v1 ? 0x3F80u : 0u;

        float xm0 = 0.f, xm1 = 0.f;                 // padded rows give x=0
        const int nmt = (np_ + 31) >> 5;

        for (int mt = 0; mt < nmt; ++mt) {
            const int src = ((mt & 1) << 5) + col;
            unsigned w0_, w1_, w2_;
            if (mt < 2) {
                w0_ = __shfl((int)Ar0, src); w1_ = __shfl((int)Ar1, src);
                w2_ = __shfl((int)Ar2, src);
            } else {
                w0_ = __shfl((int)Br0, src); w1_ = __shfl((int)Br1, src);
                w2_ = __shfl((int)Br2, src);
            }
            uint4v av = {lo ? w0_ : 0u, lo ? w1_ : 0u, lo ? w2_ : 0u, 0u};
            bf16x8 afr = __builtin_bit_cast(bf16x8, av);

            f32x16 c0 = __builtin_amdgcn_mfma_f32_32x32x16_bf16(afr, bfr0, cz, 0, 0, 0);
#pragma unroll
            for (int r = 0; r < 16; r += 2)
                xm0 = fmaxf(xm0, fmaxf(c0[r], c0[r + 1]));
            f32x16 c1 = __builtin_amdgcn_mfma_f32_32x32x16_bf16(afr, bfr1, cz, 0, 0, 0);
#pragma unroll
            for (int r = 0; r < 16; r += 2)
                xm1 = fmaxf(xm1, fmaxf(c1[r], c1[r + 1]));
        }

        xm0 = fmaxf(xm0, __shfl_xor(xm0, 32));
        xm1 = fmaxf(xm1, __shfl_xor(xm1, 32));

        out[(size_t)pv * OUT_CH + lane] = fmaxf((lo ? xm0 : xm1) + shf, 0.f);
    }
}

extern "C" void kernel_launch(void* const* d_in, const int* in_sizes, int n_in,
                              void* d_out, int out_size, void* d_ws, size_t ws_size,
                              hipStream_t stream) {
    const float4* feat = (const float4*)d_in[0];
    const int* npts    = (const int*)d_in[1];
    const int* coors   = (const int*)d_in[2];
    const float* W     = (const float*)d_in[3];
    const float* gamma = (const float*)d_in[4];
    const float* beta  = (const float*)d_in[5];

    double* tot  = (double*)d_ws;                         // 54 doubles
    float4* meta = (float4*)((char*)d_ws + 512);          // 2*24000 float4

    (void)hipMemsetAsync(tot, 0, 54 * sizeof(double), stream);
    pfn_stats<<<G1, 256, 0, stream>>>(feat, npts, coors, meta, tot);
    pfn_apply<<<G2, 256, 0, stream>>>(feat, meta, tot, W, gamma, beta, (float*)d_out);
}

// Round 10
// 53.093 us; speedup vs baseline: 1.0875x; 1.0875x over previous
//
#include <hip/hip_runtime.h>
#include <math.h>

#define NP 100
#define NPILLAR 24000
#define OUT_CH 64
#define NTOTAL 2400000.0            // bs*V*P
#define VXc 0.2f
#define VYc 0.2f
#define XOFF 0.1f
#define YOFF (-39.9f)
#define BN_EPS 1e-3
#define G1 768                      // fused kernel blocks (3072 waves, ~7.8 pillars each)
#define NW1 (G1 * 4)
#define G3 1536                     // affine kernel blocks (one elem pass)

typedef __attribute__((ext_vector_type(8))) short bf16x8;
typedef __attribute__((ext_vector_type(16))) float f32x16;
typedef __attribute__((ext_vector_type(4))) unsigned int uint4v;

__device__ __forceinline__ unsigned int f2bf(float x) {
    unsigned int b = __builtin_bit_cast(unsigned int, x);
    b += 0x7FFFu + ((b >> 16) & 1u);   // RNE
    return b >> 16;
}
__device__ __forceinline__ unsigned int pk2(float a, float b) {
    return f2bf(a) | (f2bf(b) << 16);
}

__device__ __forceinline__ void build_f(const float4 p, float mx, float my, float mz,
                                        float cx, float cy, float* f) {
    f[0] = p.x; f[1] = p.y; f[2] = p.z; f[3] = p.w;
    f[4] = p.x - mx; f[5] = p.y - my; f[6] = p.z - mz;
    f[7] = p.x - cx; f[8] = p.y - cy;
}

__device__ __forceinline__ void moments(float* s, const float* f) {
    int k = 9;
#pragma unroll
    for (int i = 0; i < 9; ++i) {
        s[i] += f[i];
#pragma unroll
        for (int j = i; j < 9; ++j) { s[k] = fmaf(f[i], f[j], s[k]); ++k; }
    }
}

// ---- K1: ONE pillar pass: 54 moments + MFMA xmax/xmin (unnormalized) -------
__global__ __launch_bounds__(256) void pfn_fused(
    const float4* __restrict__ feat, const int* __restrict__ npts,
    const int* __restrict__ coors, const float* __restrict__ W,
    float* __restrict__ xmax_ws, float* __restrict__ xmin_ws,
    double* __restrict__ tot)
{
    const int tid = threadIdx.x;
    const int lane = tid & 63;
    const int wv = tid >> 6;
    const int gw = blockIdx.x * 4 + wv;
    const int col = lane & 31;
    const int kbase = (lane >> 5) * 8;
    const bool lo = (lane < 32);

    // B fragments: unscaled W, lane holds B[k=kbase+i][col(+32)]
    bf16x8 bfr0, bfr1;
#pragma unroll
    for (int i = 0; i < 8; ++i) {
        int k = kbase + i;
        float w0 = (k < 9) ? W[k * OUT_CH + col] : 0.f;
        float w1 = (k < 9) ? W[k * OUT_CH + 32 + col] : 0.f;
        bfr0[i] = (short)f2bf(w0);
        bfr1[i] = (short)f2bf(w1);
    }
    f32x16 cz;
#pragma unroll
    for (int i = 0; i < 16; ++i) cz[i] = 0.f;

    float s[54];
#pragma unroll
    for (int i = 0; i < 54; ++i) s[i] = 0.f;

    for (int pv = gw; pv < NPILLAR; pv += NW1) {
        const float4* fp = feat + (size_t)pv * NP;
        float4 p0 = fp[lane];
        float4 p1 = (lane + 64 < NP) ? fp[lane + 64] : make_float4(0.f, 0.f, 0.f, 0.f);

        // reference: mean sums ALL NP points, divides by max(n,1)
        float sx = p0.x + p1.x, sy = p0.y + p1.y, sz = p0.z + p1.z;
#pragma unroll
        for (int off = 32; off; off >>= 1) {
            sx += __shfl_xor(sx, off);
            sy += __shfl_xor(sy, off);
            sz += __shfl_xor(sz, off);
        }
        int np_ = npts[pv];
        if (np_ > NP) np_ = NP;
        float inv = 1.f / fmaxf((float)np_, 1.f);
        float mx = sx * inv, my = sy * inv, mz = sz * inv;
        float cx = (float)coors[pv * 4 + 2] * VXc + XOFF;
        float cy = (float)coors[pv * 4 + 1] * VYc + YOFF;

        // augmented features + moments + bf16 A rows
        unsigned int A[5], B[5];
        {
            float f[9];
            if (lane < np_) {
                build_f(p0, mx, my, mz, cx, cy, f);
                moments(s, f);
                A[0] = pk2(f[0], f[1]); A[1] = pk2(f[2], f[3]);
                A[2] = pk2(f[4], f[5]); A[3] = pk2(f[6], f[7]);
                A[4] = f2bf(f[8]);
            } else {
#pragma unroll
                for (int i = 0; i < 5; ++i) A[i] = 0u;
            }
            if (lane + 64 < np_) {
                build_f(p1, mx, my, mz, cx, cy, f);
                moments(s, f);
                B[0] = pk2(f[0], f[1]); B[1] = pk2(f[2], f[3]);
                B[2] = pk2(f[4], f[5]); B[3] = pk2(f[6], f[7]);
                B[4] = f2bf(f[8]);
            } else {
#pragma unroll
                for (int i = 0; i < 5; ++i) B[i] = 0u;
            }
        }

        // MFMA x = feats @ W, track unnormalized max AND min (scale sign unknown)
        float xmx0 = 0.f, xmx1 = 0.f;   // padded x=0 rows always exist (np<=99)
        float xmn0 = 0.f, xmn1 = 0.f;
        const int nmt = (np_ + 31) >> 5;

        for (int mt = 0; mt < nmt; ++mt) {
            const int src = ((mt & 1) << 5) + col;
            unsigned int w0, w1, w2, w3, w4;
            if (mt < 2) {
                w0 = __shfl((int)A[0], src); w1 = __shfl((int)A[1], src);
                w2 = __shfl((int)A[2], src); w3 = __shfl((int)A[3], src);
                w4 = __shfl((int)A[4], src);
            } else {
                w0 = __shfl((int)B[0], src); w1 = __shfl((int)B[1], src);
                w2 = __shfl((int)B[2], src); w3 = __shfl((int)B[3], src);
                w4 = __shfl((int)B[4], src);
            }
            uint4v av = {lo ? w0 : w4, lo ? w1 : 0u, lo ? w2 : 0u, lo ? w3 : 0u};
            bf16x8 afr = __builtin_bit_cast(bf16x8, av);

            f32x16 c0 = __builtin_amdgcn_mfma_f32_32x32x16_bf16(afr, bfr0, cz, 0, 0, 0);
#pragma unroll
            for (int r = 0; r < 16; r += 2) {
                xmx0 = fmaxf(xmx0, fmaxf(c0[r], c0[r + 1]));
                xmn0 = fminf(xmn0, fminf(c0[r], c0[r + 1]));
            }
            f32x16 c1 = __builtin_amdgcn_mfma_f32_32x32x16_bf16(afr, bfr1, cz, 0, 0, 0);
#pragma unroll
            for (int r = 0; r < 16; r += 2) {
                xmx1 = fmaxf(xmx1, fmaxf(c1[r], c1[r + 1]));
                xmn1 = fminf(xmn1, fminf(c1[r], c1[r + 1]));
            }
        }

        xmx0 = fmaxf(xmx0, __shfl_xor(xmx0, 32));
        xmx1 = fmaxf(xmx1, __shfl_xor(xmx1, 32));
        xmn0 = fminf(xmn0, __shfl_xor(xmn0, 32));
        xmn1 = fminf(xmn1, __shfl_xor(xmn1, 32));

        xmax_ws[(size_t)pv * OUT_CH + lane] = lo ? xmx0 : xmx1;
        xmin_ws[(size_t)pv * OUT_CH + lane] = lo ? xmn0 : xmn1;
    }

    // block moment partials -> device atomics
#pragma unroll
    for (int i = 0; i < 54; ++i) {
#pragma unroll
        for (int off = 32; off; off >>= 1) s[i] += __shfl_xor(s[i], off);
    }
    __shared__ float red[4][54];
    if (lane == 0) {
#pragma unroll
        for (int i = 0; i < 54; ++i) red[wv][i] = s[i];
    }
    __syncthreads();
    if (tid < 54) {
        atomicAdd(&tot[tid],
                  (double)(red[0][tid] + red[1][tid] + red[2][tid] + red[3][tid]));
    }
}

// ---- K2: 1 block, 64 threads: scale/shift from moments ---------------------
__global__ void pfn_finalize(const double* __restrict__ tot,
                             const float* __restrict__ W,
                             const float* __restrict__ gamma,
                             const float* __restrict__ beta,
                             float* __restrict__ scsh)
{
    const int c = threadIdx.x;   // 64
    double w[9];
#pragma unroll
    for (int i = 0; i < 9; ++i) w[i] = (double)W[i * OUT_CH + c];
    double mean = 0.0;
#pragma unroll
    for (int i = 0; i < 9; ++i) mean += tot[i] * w[i];
    mean /= NTOTAL;
    double ex2 = 0.0;
    int k = 9;
#pragma unroll
    for (int i = 0; i < 9; ++i) {
#pragma unroll
        for (int j = i; j < 9; ++j) {
            ex2 += (i == j ? 1.0 : 2.0) * tot[k] * w[i] * w[j];
            ++k;
        }
    }
    ex2 /= NTOTAL;
    double var = ex2 - mean * mean;
    double scale = (double)gamma[c] / sqrt(var + BN_EPS);
    double shift = (double)beta[c] - mean * scale;
    scsh[c] = (float)scale;
    scsh[OUT_CH + c] = (float)shift;
}

// ---- K3: pure streaming affine+relu (no pillar loop) -----------------------
__global__ __launch_bounds__(256) void pfn_affine(
    const float4* __restrict__ xmax_ws, const float4* __restrict__ xmin_ws,
    const float* __restrict__ scsh, float4* __restrict__ out)
{
    __shared__ float sc_s[64], sh_s[64];
    if (threadIdx.x < 64) {
        sc_s[threadIdx.x] = scsh[threadIdx.x];
        sh_s[threadIdx.x] = scsh[OUT_CH + threadIdx.x];
    }
    __syncthreads();

    const int N4 = NPILLAR * OUT_CH / 4;     // 384000 float4
    int i = blockIdx.x * 256 + threadIdx.x;
    if (i >= N4) return;
    float4 mx = xmax_ws[i];
    float4 mn = xmin_ws[i];
    const int c = (i & 15) * 4;
    float4 r;
    {
        float sc = sc_s[c + 0], sh = sh_s[c + 0];
        r.x = fmaxf(fmaf(sc, (sc >= 0.f) ? mx.x : mn.x, sh), 0.f);
    }
    {
        float sc = sc_s[c + 1], sh = sh_s[c + 1];
        r.y = fmaxf(fmaf(sc, (sc >= 0.f) ? mx.y : mn.y, sh), 0.f);
    }
    {
        float sc = sc_s[c + 2], sh = sh_s[c + 2];
        r.z = fmaxf(fmaf(sc, (sc >= 0.f) ? mx.z : mn.z, sh), 0.f);
    }
    {
        float sc = sc_s[c + 3], sh = sh_s[c + 3];
        r.w = fmaxf(fmaf(sc, (sc >= 0.f) ? mx.w : mn.w, sh), 0.f);
    }
    out[i] = r;
}

extern "C" void kernel_launch(void* const* d_in, const int* in_sizes, int n_in,
                              void* d_out, int out_size, void* d_ws, size_t ws_size,
                              hipStream_t stream) {
    const float4* feat = (const float4*)d_in[0];
    const int* npts    = (const int*)d_in[1];
    const int* coors   = (const int*)d_in[2];
    const float* W     = (const float*)d_in[3];
    const float* gamma = (const float*)d_in[4];
    const float* beta  = (const float*)d_in[5];

    double* tot    = (double*)d_ws;                              // 54 doubles
    float* scsh    = (float*)((char*)d_ws + 512);                // 128 f32
    float* xmax_ws = (float*)((char*)d_ws + 4096);               // 24000*64 f32
    float* xmin_ws = xmax_ws + (size_t)NPILLAR * OUT_CH;

    (void)hipMemsetAsync(tot, 0, 54 * sizeof(double), stream);
    pfn_fused<<<G1, 256, 0, stream>>>(feat, npts, coors, W, xmax_ws, xmin_ws, tot);
    pfn_finalize<<<1, 64, 0, stream>>>(tot, W, gamma, beta, scsh);
    pfn_affine<<<G3, 256, 0, stream>>>((const float4*)xmax_ws, (const float4*)xmin_ws,
                                       scsh, (float4*)d_out);
}